// Round 10
// baseline (51.920 us; speedup 1.0000x reference)
//
#include <hip/hip_runtime.h>

#define NCLS 256
#define NDF  512
#define BSZ  1024
#define ALP  0.1f

// score[b,c] = s1[b,c]-s1[b,t] + 0.5*ALP*(R[t,c]-R[t,t]),  t=gt[b]
// SINGLE DISPATCH, zero cross-block deps: block (bm,bn) = 32 samples x 32 cols.
// Slot i = sample i's class t_i. Per 128-dim chunk: per-slot order-preserving
// var recurrence (8 thr/slot x 16 dims) -> stage bf16 tiles {df, fc_c,
// -2*fc_t*var, var, fc_c^2} -> 3 MFMA/k-step: accS += df*fc_c,
// accR += (-2 fc_t var)*fc_c + var*fc_c^2. accR IS R[t_i, c_j] register-aligned.
// bias1 (s1[b,t]) and Rtt (R[t,t] = -sum fc_t^2 var) computed by the recurrence
// threads in the SAME bf16 rounding -> out[b,t] ~ 0 to association error.
// Redundancy: var recomputed per col-tile (8x) - cheaper than a 2nd dispatch
// (R6-R9 plateaued at 25-27us on dispatch overhead).
// MFMA mapping m89/m97-verified, r6-r9-validated (absmax 1.0).

typedef __attribute__((ext_vector_type(8))) short bf16x8;
typedef __attribute__((ext_vector_type(4))) float f32x4;

// RNE fp32->bf16, matching MFMA operand rounding everywhere.
__device__ __forceinline__ unsigned rne_pk(float lo, float hi) {
    union { float f; unsigned u; } a, b;
    a.f = lo; b.f = hi;
    unsigned ua = (a.u + 0x7FFFu + ((a.u >> 16) & 1u)) >> 16;
    unsigned ub = (b.u + 0x7FFFu + ((b.u >> 16) & 1u)) & 0xFFFF0000u;
    return ua | ub;
}
__device__ __forceinline__ uint4 pk16(float4 p, float4 q) {
    uint4 r;
    r.x = rne_pk(p.x, p.y); r.y = rne_pk(p.z, p.w);
    r.z = rne_pk(q.x, q.y); r.w = rne_pk(q.z, q.w);
    return r;
}
__device__ __forceinline__ uint4 pk8a(const float* x) {   // 8 floats -> 8 bf16
    uint4 r;
    r.x = rne_pk(x[0], x[1]); r.y = rne_pk(x[2], x[3]);
    r.z = rne_pk(x[4], x[5]); r.w = rne_pk(x[6], x[7]);
    return r;
}
__device__ __forceinline__ float bf16r(float x) {
    union { float f; unsigned u; } c; c.f = x;
    c.u = (c.u + 0x7FFFu + ((c.u >> 16) & 1u)) & 0xFFFF0000u;
    return c.f;
}
__device__ __forceinline__ void unpk4(float* o, float4 q) {
    o[0] = q.x; o[1] = q.y; o[2] = q.z; o[3] = q.w;
}

// grid 256 x 256: bm = bid>>3 (sample tile), bn = bid&7 (col tile).
__global__ __launch_bounds__(256) void fused_one(const float* __restrict__ df,
                                                 const int* __restrict__ gt,
                                                 const float* __restrict__ fc,
                                                 float* __restrict__ out) {
    __shared__ union {
        struct {                                   // 5 tiles x 32 rows x 128 bf16
            alignas(16) char dfT[32 * 256];        // A: df
            alignas(16) char fcT[32 * 256];        // B: fc (col classes)
            alignas(16) char alT[32 * 256];        // A: -2*fc_t*var
            alignas(16) char aqT[32 * 256];        // A: var
            alignas(16) char bqT[32 * 256];        // B: fc^2
        } t;
        struct { unsigned long long bmap[256 * 16]; int gts[BSZ]; } p;  // prepass
    } sm;
    __shared__ unsigned long long slotmap[32 * 16];  // persistent per-slot bitmaps
    __shared__ float biasL[32], rttL[32];

    const int tid = threadIdx.x;
    const int bm = blockIdx.x >> 3, bn = blockIdx.x & 7;
    const int slot = tid >> 3, ln8 = tid & 7;

    // --------------------------- prepass (once) ----------------------------
    for (int i = tid; i < 256 * 16; i += 256) sm.p.bmap[i] = 0ull;
    for (int i = tid; i < BSZ; i += 256) sm.p.gts[i] = gt[i];
    __syncthreads();
    for (int i = tid; i < BSZ; i += 256)
        atomicOr(&sm.p.bmap[sm.p.gts[i] * 16 + (i >> 6)], 1ull << (i & 63));
    __syncthreads();
    const int myt = sm.p.gts[bm * 32 + slot];        // this slot's class
    for (int u = tid; u < 512; u += 256)             // compact per-slot bitmaps
        slotmap[u] = sm.p.bmap[sm.p.gts[bm * 32 + (u >> 4)] * 16 + (u & 15)];
    __syncthreads();                                  // prepass region now free

    // roles / layout
    const int sampleg = bm * 32 + slot;
    const int dbyte = ln8 * 32;                      // 16 bf16 within 256B row
    const int swz = (slot & 7) << 4;
    char* dfR = sm.t.dfT + slot * 256;
    char* fcR = sm.t.fcT + slot * 256;
    char* alR = sm.t.alT + slot * 256;
    char* aqR = sm.t.aqT + slot * 256;
    char* bqR = sm.t.bqT + slot * 256;

    const int lane = tid & 63, wv = tid >> 6;
    const int wm = (wv >> 1) * 16, wn = (wv & 1) * 16;  // wave quadrant
    const int fr = lane & 15, fkb = (lane >> 4) * 16, fswz = (fr & 7) << 4;

    f32x4 accS = 0.f, accR = 0.f;
    float bias = 0.f, rtt = 0.f;

#pragma unroll 1
    for (int ch = 0; ch < 4; ++ch) {
        const int dim0 = ch * 128 + ln8 * 16;        // this thread's 16 dims
        // ---- staging loads (issue early; latency hides under recurrence) ----
        const float* pd = df + sampleg * NDF + dim0;
        const float* pc = fc + (bn * 32 + slot) * NDF + dim0;
        const float* pt = fc + myt * NDF + dim0;
        const float4 dv0 = ((const float4*)pd)[0], dv1 = ((const float4*)pd)[1],
                     dv2 = ((const float4*)pd)[2], dv3 = ((const float4*)pd)[3];
        const float4 cv0 = ((const float4*)pc)[0], cv1 = ((const float4*)pc)[1],
                     cv2 = ((const float4*)pc)[2], cv3 = ((const float4*)pc)[3];
        const float4 tv0 = ((const float4*)pt)[0], tv1 = ((const float4*)pt)[1],
                     tv2 = ((const float4*)pt)[2], tv3 = ((const float4*)pt)[3];

        // independent tiles can be written as soon as loads land (barrier from
        // previous chunk's MFMA already passed)
        *(uint4*)(dfR + (dbyte ^ swz)) = pk16(dv0, dv1);
        *(uint4*)(dfR + ((dbyte + 16) ^ swz)) = pk16(dv2, dv3);
        *(uint4*)(fcR + (dbyte ^ swz)) = pk16(cv0, cv1);
        *(uint4*)(fcR + ((dbyte + 16) ^ swz)) = pk16(cv2, cv3);
        {
            float c16[16], q16[16];
            unpk4(c16 + 0, cv0); unpk4(c16 + 4, cv1); unpk4(c16 + 8, cv2); unpk4(c16 + 12, cv3);
#pragma unroll
            for (int j = 0; j < 16; ++j) q16[j] = c16[j] * c16[j];
            *(uint4*)(bqR + (dbyte ^ swz)) = pk8a(q16);
            *(uint4*)(bqR + ((dbyte + 16) ^ swz)) = pk8a(q16 + 8);
        }

        // ---- per-slot sequential running-var recurrence (16 dims) ----
        float m16[16], v16[16];
#pragma unroll
        for (int j = 0; j < 16; ++j) { m16[j] = 0.f; v16[j] = 0.f; }
        {
            float nf = 0.f;
            int w = 0;
            unsigned long long bits = slotmap[slot * 16];
            auto next = [&]() -> int {
                while (bits == 0ull) {
                    if (w >= 15) return -1;
                    bits = slotmap[slot * 16 + (++w)];
                }
                const int b = __ffsll((unsigned long long)bits) - 1;
                bits &= bits - 1ull;
                return (w << 6) + b;
            };
            int cur = next();
            float f[16];
            if (cur >= 0) {
                const float* p = df + cur * NDF + dim0;
                unpk4(f + 0, ((const float4*)p)[0]); unpk4(f + 4, ((const float4*)p)[1]);
                unpk4(f + 8, ((const float4*)p)[2]); unpk4(f + 12, ((const float4*)p)[3]);
            }
            while (cur >= 0) {
                const int nxt = next();
                float g[16];
                if (nxt >= 0) {   // prefetch next sample before dependent update
                    const float* p = df + nxt * NDF + dim0;
                    unpk4(g + 0, ((const float4*)p)[0]); unpk4(g + 4, ((const float4*)p)[1]);
                    unpk4(g + 8, ((const float4*)p)[2]); unpk4(g + 12, ((const float4*)p)[3]);
                }
                const float c2 = 1.0f / (nf + 1.0f);
                const float c1 = nf * c2;
                const float c12 = c1 * c2;
#pragma unroll
                for (int j = 0; j < 16; ++j) {
                    m16[j] = m16[j] * c1 + f[j] * c2;   // == f when nf==0
                    const float a = f[j] - m16[j];
                    v16[j] = v16[j] * c1 + a * a * c12;
                }
                nf += 1.0f;
#pragma unroll
                for (int j = 0; j < 16; ++j) f[j] = g[j];
                cur = nxt;
            }
        }

        // ---- A-operand tiles + bias/Rtt partials (same bf16 rounding) ----
        {
            float t16[16], d16[16], l16[16];
            unpk4(t16 + 0, tv0); unpk4(t16 + 4, tv1); unpk4(t16 + 8, tv2); unpk4(t16 + 12, tv3);
            unpk4(d16 + 0, dv0); unpk4(d16 + 4, dv1); unpk4(d16 + 8, dv2); unpk4(d16 + 12, dv3);
#pragma unroll
            for (int j = 0; j < 16; ++j) {
                l16[j] = -2.f * t16[j] * v16[j];
                bias = fmaf(bf16r(d16[j]), bf16r(t16[j]), bias);
                // Rtt = R[t,t]: quad term fc_t^2*var + linear term (-2 fc_t var)*fc_t,
                // with operands rounded exactly like the MFMA tiles.
                rtt = fmaf(bf16r(t16[j] * t16[j]), bf16r(v16[j]), rtt);
                rtt = fmaf(bf16r(l16[j]), bf16r(t16[j]), rtt);
            }
            *(uint4*)(alR + (dbyte ^ swz)) = pk8a(l16);
            *(uint4*)(alR + ((dbyte + 16) ^ swz)) = pk8a(l16 + 8);
            *(uint4*)(aqR + (dbyte ^ swz)) = pk8a(v16);
            *(uint4*)(aqR + ((dbyte + 16) ^ swz)) = pk8a(v16 + 8);
        }
        __syncthreads();

        // ---- MFMA: 4 k-steps x {s1, R-linear, R-quad} ----
#pragma unroll
        for (int s = 0; s < 4; ++s) {
            const int kb = (s * 64 + fkb) ^ fswz;
            const bf16x8 aS = *(const bf16x8*)(sm.t.dfT + (wm + fr) * 256 + kb);
            const bf16x8 bC = *(const bf16x8*)(sm.t.fcT + (wn + fr) * 256 + kb);
            const bf16x8 aL = *(const bf16x8*)(sm.t.alT + (wm + fr) * 256 + kb);
            const bf16x8 aQ = *(const bf16x8*)(sm.t.aqT + (wm + fr) * 256 + kb);
            const bf16x8 bQ = *(const bf16x8*)(sm.t.bqT + (wn + fr) * 256 + kb);
            accS = __builtin_amdgcn_mfma_f32_16x16x32_bf16(aS, bC, accS, 0, 0, 0);
            accR = __builtin_amdgcn_mfma_f32_16x16x32_bf16(aL, bC, accR, 0, 0, 0);
            accR = __builtin_amdgcn_mfma_f32_16x16x32_bf16(aQ, bQ, accR, 0, 0, 0);
        }
        __syncthreads();   // tiles reusable next chunk
    }

    // ---- reduce bias/Rtt across the slot's 8 threads (xor stays in group) ----
    bias += __shfl_xor(bias, 1); bias += __shfl_xor(bias, 2); bias += __shfl_xor(bias, 4);
    rtt += __shfl_xor(rtt, 1);   rtt += __shfl_xor(rtt, 2);   rtt += __shfl_xor(rtt, 4);
    if (ln8 == 0) { biasL[slot] = bias; rttL[slot] = rtt; }
    __syncthreads();

    // ---- fused epilogue: out = (s1 - s1[b,t]) + 0.5*ALP*(R[t,c] - R[t,t]) ----
#pragma unroll
    for (int r = 0; r < 4; ++r) {
        const int row = wm + (lane >> 4) * 4 + r;            // local sample row
        out[(bm * 32 + row) * NCLS + bn * 32 + wn + fr] =
            (accS[r] - biasL[row]) + 0.5f * ALP * (accR[r] - rttL[row]);
    }
}

// ---------------------------------------------------------------------------
extern "C" void kernel_launch(void* const* d_in, const int* in_sizes, int n_in,
                              void* d_out, int out_size, void* d_ws, size_t ws_size,
                              hipStream_t stream) {
    const float* df = (const float*)d_in[0];
    const int* gt = (const int*)d_in[1];
    const float* fc = (const float*)d_in[2];
    float* out = (float*)d_out;

    fused_one<<<256, 256, 0, stream>>>(df, gt, fc, out);   // single dispatch, no ws
}